// Round 6
// baseline (570.997 us; speedup 1.0000x reference)
//
#include <hip/hip_runtime.h>
#include <math.h>

#pragma clang fp contract(off)

typedef unsigned int u32;

#define N_NEUR 262144              // 32*8192 neurons
#define TT     128                 // time steps
#define OB     ((size_t)N_NEUR * TT)  // floats in spike region of out
#define SB     512                 // step-kernel blocks
#define ST     128                 // step-kernel threads (2 waves)

__device__ __forceinline__ float wredf(float v) {
#pragma unroll
  for (int o = 32; o; o >>= 1) v += __shfl_xor(v, o);
  return v;
}
__device__ __forceinline__ int wredi(int v) {
#pragma unroll
  for (int o = 32; o; o >>= 1) v += __shfl_xor(v, o);
  return v;
}

// in[n][t] -> inT[t][n].  inT lives in out[0..OB) (expand overwrites it later).
__global__ void snn_transpose(const float* __restrict__ in, float* __restrict__ inT)
{
  __shared__ float tile[64][65];
  const int n0  = (int)(blockIdx.x >> 1) * 64;   // 4096 n-tiles
  const int t0  = (int)(blockIdx.x & 1) * 64;    // 2 t-tiles
  const int tid = threadIdx.x;                   // 256
  const int c4  = tid & 15, rr = tid >> 4;
#pragma unroll
  for (int i = 0; i < 4; ++i) {
    const int r = i * 16 + rr;
    const float4 v = *(const float4*)(in + (size_t)(n0 + r) * TT + t0 + 4 * c4);
    tile[r][4*c4+0] = v.x; tile[r][4*c4+1] = v.y;
    tile[r][4*c4+2] = v.z; tile[r][4*c4+3] = v.w;
  }
  __syncthreads();
#pragma unroll
  for (int i = 0; i < 4; ++i) {
    const int tr = i * 16 + rr;
    float4 v;
    v.x = tile[4*c4+0][tr]; v.y = tile[4*c4+1][tr];
    v.z = tile[4*c4+2][tr]; v.w = tile[4*c4+3][tr];
    *(float4*)(inT + (size_t)(t0 + tr) * N_NEUR + n0 + 4 * c4) = v;
  }
}

__launch_bounds__(ST, 8)
__global__ void snn_step(const float* __restrict__ inT, const float* __restrict__ tsp,
                         const float* __restrict__ abp, float* __restrict__ out,
                         float* __restrict__ syn, float* __restrict__ mem,
                         float* __restrict__ ad, u32* __restrict__ bits2,
                         float* __restrict__ g_ema, u32* __restrict__ g_cnt,
                         float* __restrict__ wm, float* __restrict__ wt,
                         float* __restrict__ wa, int t)
{
#pragma clang fp contract(off)
  const int tid  = threadIdx.x;
  const int bid  = blockIdx.x;
  const int th   = bid * ST + tid;   // 0..65535, 4 neurons each
  const int lane = tid & 63;
  const int wv   = tid >> 6;

  __shared__ float sf[6];
  __shared__ int   si[2];

  // ---- reconstruct ema for this step from step t-1's exact integer counts ----
  float ema = 0.0f;
  if (t > 0) {
    const u32* pc = g_cnt + (size_t)(t - 1) * SB;
    int c = (int)(pc[tid] + pc[tid + 128] + pc[tid + 256] + pc[tid + 384]);
    c = wredi(c);
    if (lane == 0) si[wv] = c;
    __syncthreads();
    const int ctot = si[0] + si[1];                       // identical in every block
    const float mean = (float)ctot * 3.814697265625e-06f; // *2^-18, exact
    // XLA fuses 0.99*ema + 0.01*mean -> fma(0.99, ema, 0.01*mean)
    ema = __builtin_fmaf(0.99f, g_ema[t - 1], 0.01f * mean);
  }

  // block 0 additionally folds step t-1's trace partials (deterministic order)
  if (bid == 0 && t > 0) {
    const float* pm = wm + (size_t)(t - 1) * SB;
    const float* pt = wt + (size_t)(t - 1) * SB;
    float fm = ((pm[tid] + pm[tid + 128]) + pm[tid + 256]) + pm[tid + 384];
    float ft = ((pt[tid] + pt[tid + 128]) + pt[tid + 256]) + pt[tid + 384];
    fm = wredf(fm); ft = wredf(ft);
    __shared__ float sg[4];
    if (lane == 0) { sg[wv] = fm; sg[2 + wv] = ft; }
    __syncthreads();
    if (tid == 0) {
      out[OB + (t - 1)]      = (sg[0] + sg[1]) * 3.814697265625e-06f;
      out[OB + TT + (t - 1)] = (sg[2] + sg[3]) * 3.814697265625e-06f;
    }
  }

  // A-constants: correctly-rounded expf of the f32 quotients -0.001f/0.02f etc.
  // (glibc expf libcall at XLA trace time).  Hard-coded bit patterns:
  //   alpha = expf(-0.050000004470348358f) = 15958981 * 2^-24
  //   beta  = expf(-0.20000001788139343f)  = 13736022 * 2^-24
  //   gamma = expf(-0.010000000707805157f) = 16610280 * 2^-24
  const float alp = __uint_as_float(0x3F7383C5u);  // 0.95122939348220825
  const float bet = __uint_as_float(0x3F519856u);  // 0.81873071193695068
  const float gma = __uint_as_float(0x3F7D73E8u);  // 0.99004977941513062
  const float omg = 1.0f - gma;                    // exact (Sterbenz)

  const float homeo = 0.1f * fmaxf(ema - 0.01f, 0.0f);
  const float sc    = (tsp[0] + homeo) + abp[0];   // 1.0*ts == ts exactly

  float4 s4, m4, a4;
  if (t) {
    s4 = ((const float4*)syn)[th];
    m4 = ((const float4*)mem)[th];
    a4 = ((const float4*)ad)[th];
  } else {
    s4 = make_float4(0.f, 0.f, 0.f, 0.f); m4 = s4; a4 = s4;
  }

  const float4 i4 = ((const float4*)(inT + (size_t)t * N_NEUR))[th];

  int cnt = 0; u32 nib = 0; float msum = 0.f, tsum = 0.f;

  // FMA body exactly as XLA:CPU DAG-fuses it (FPOpFusion::Fast):
  //   S = fma(beta,S,I); M = fma(alpha,M,S); A = fma(gamma,A, omg*M);
  //   th = fma(0.1,A,sc);  reset: M - th (exact either form for sp in {0,1})
#define STEP1(S, M, A, I, J) {                          \
    S = __builtin_fmaf(bet, S, I);                      \
    M = __builtin_fmaf(alp, M, S);                      \
    const float aw_ = omg * M;                          \
    A = __builtin_fmaf(gma, A, aw_);                    \
    const float th_ = __builtin_fmaf(0.1f, A, sc);      \
    const bool sp = (M >= th_);                         \
    if (sp) { M = M - th_; nib |= 1u << (J); cnt++; }   \
    msum += M; tsum += th_; }

  STEP1(s4.x, m4.x, a4.x, i4.x, 0)
  STEP1(s4.y, m4.y, a4.y, i4.y, 1)
  STEP1(s4.z, m4.z, a4.z, i4.z, 2)
  STEP1(s4.w, m4.w, a4.w, i4.w, 3)
#undef STEP1

  ((float4*)syn)[th] = s4;
  ((float4*)mem)[th] = m4;
  ((float4*)ad)[th]  = a4;

  // pack 32 spike bits (neurons 32*(th>>3)..+31) -> bits2[word][t]
  u32 word = nib << (4 * (tid & 7));
  word |= (u32)__shfl_xor((int)word, 1);
  word |= (u32)__shfl_xor((int)word, 2);
  word |= (u32)__shfl_xor((int)word, 4);
  if ((tid & 7) == 0) bits2[(size_t)(th >> 3) * TT + t] = word;

  const float m_ = wredf(msum);
  const float t_ = wredf(tsum);
  const int   c_ = wredi(cnt);
  const float a_ = (t == TT - 1) ? wredf(((a4.x + a4.y) + a4.z) + a4.w) : 0.f;

  __syncthreads();   // si/sf reuse safe after ema-fold reads
  if (lane == 0) { sf[wv] = m_; sf[2 + wv] = t_; sf[4 + wv] = a_; si[wv] = c_; }
  __syncthreads();
  if (tid == 0) {
    wm[(size_t)t * SB + bid]    = sf[0] + sf[1];
    wt[(size_t)t * SB + bid]    = sf[2] + sf[3];
    g_cnt[(size_t)t * SB + bid] = (u32)(si[0] + si[1]);
    if (t == TT - 1) wa[bid] = sf[4] + sf[5];
    g_ema[t] = ema;   // same value from every block; read by kernel t+1
  }
}

__launch_bounds__(ST, 8)
__global__ void snn_finish(const u32* __restrict__ g_cnt, const float* __restrict__ g_ema,
                           const float* __restrict__ wm, const float* __restrict__ wt,
                           const float* __restrict__ wa, float* __restrict__ out)
{
#pragma clang fp contract(off)
  const int tid = threadIdx.x, lane = tid & 63, wv = tid >> 6;
  __shared__ float sf[6];
  __shared__ int   si[2];
  const int t = TT - 1;
  const u32* pc = g_cnt + (size_t)t * SB;
  int c = (int)(pc[tid] + pc[tid + 128] + pc[tid + 256] + pc[tid + 384]);
  c = wredi(c);
  const float* pm = wm + (size_t)t * SB;
  const float* pt = wt + (size_t)t * SB;
  float fm = ((pm[tid] + pm[tid + 128]) + pm[tid + 256]) + pm[tid + 384];
  float ft = ((pt[tid] + pt[tid + 128]) + pt[tid + 256]) + pt[tid + 384];
  float fa = ((wa[tid] + wa[tid + 128]) + wa[tid + 256]) + wa[tid + 384];
  fm = wredf(fm); ft = wredf(ft); fa = wredf(fa);
  if (lane == 0) { si[wv] = c; sf[wv] = fm; sf[2 + wv] = ft; sf[4 + wv] = fa; }
  __syncthreads();
  if (tid == 0) {
    const float inv  = 3.814697265625e-06f;  // 2^-18
    const float mean = (float)(si[0] + si[1]) * inv;
    const float emaF = __builtin_fmaf(0.99f, g_ema[t], 0.01f * mean); // final ema
    out[OB + t]          = (sf[0] + sf[1]) * inv;
    out[OB + TT + t]     = (sf[2] + sf[3]) * inv;
    out[OB + 2 * TT]     = emaF;
    out[OB + 2 * TT + 1] = (sf[4] + sf[5]) * inv;
  }
}

// bits2[word][t] -> float spikes [n][t]; uint4 reads + float4 writes, coalesced.
// Overwrites out[0..OB) (which held inT; all reads of inT are already done).
__global__ void snn_expand(const u32* __restrict__ bits2, float* __restrict__ outF)
{
  const int gtid = blockIdx.x * blockDim.x + threadIdx.x;
  const int wave = gtid >> 6, lane = gtid & 63;
  const int nwaves = (gridDim.x * blockDim.x) >> 6;
  const int nloc = lane >> 5;     // which neuron of the pair
  const int tq   = lane & 31;     // float4 chunk over t
  for (int pair = wave; pair < N_NEUR / 2; pair += nwaves) {
    const int n = 2 * pair + nloc;
    const uint4 w = *(const uint4*)(bits2 + (size_t)(n >> 5) * TT + 4 * tq);
    const int b = n & 31;
    float4 f;
    f.x = (float)((w.x >> b) & 1u);
    f.y = (float)((w.y >> b) & 1u);
    f.z = (float)((w.z >> b) & 1u);
    f.w = (float)((w.w >> b) & 1u);
    ((float4*)outF)[(size_t)n * (TT / 4) + tq] = f;
  }
}

extern "C" void kernel_launch(void* const* d_in, const int* in_sizes, int n_in,
                              void* d_out, int out_size, void* d_ws, size_t ws_size,
                              hipStream_t stream)
{
  const float* in  = (const float*)d_in[0];
  const float* tsp = (const float*)d_in[1];
  const float* abp = (const float*)d_in[2];
  float* out = (float*)d_out;
  unsigned char* ws = (unsigned char*)d_ws;

  if (ws_size < 8129024u) return;  // ~7.75 MiB scratch needed

  u32*   bits2 = (u32*)(ws);                  // 4 MiB  [8192 words][128 t]
  float* syn   = (float*)(ws + 4194304);      // 1 MiB
  float* mem   = (float*)(ws + 5242880);      // 1 MiB
  float* ad    = (float*)(ws + 6291456);      // 1 MiB
  float* wm    = (float*)(ws + 7340032);      // 256 KiB [128][512]
  float* wt    = (float*)(ws + 7602176);      // 256 KiB
  u32*   g_cnt = (u32*)(ws + 7864320);        // 256 KiB [128][512]
  float* wa    = (float*)(ws + 8126464);      // 2 KiB
  float* g_ema = (float*)(ws + 8128512);      // 512 B

  float* inT = out;  // out[0..OB) as transpose scratch; expand overwrites it later

  snn_transpose<<<dim3(8192), dim3(256), 0, stream>>>(in, inT);

  for (int t = 0; t < TT; ++t)
    snn_step<<<dim3(SB), dim3(ST), 0, stream>>>(inT, tsp, abp, out, syn, mem, ad,
                                                bits2, g_ema, g_cnt, wm, wt, wa, t);

  snn_finish<<<dim3(1), dim3(ST), 0, stream>>>(g_cnt, g_ema, wm, wt, wa, out);
  snn_expand<<<dim3(2048), dim3(256), 0, stream>>>(bits2, out);
}